// Round 1
// baseline (16.341 us; speedup 1.0000x reference)
//
#include <hip/hip_runtime.h>

// YOLOv2 loss: B=1024, S=13, A=5, C5=25. Output: scalar f32.
constexpr int kB   = 1024;
constexpr int kS   = 13;
constexpr int kA   = 5;
constexpr int kC5  = 25;
constexpr int kCells = kB * kS * kS;       // 173056
constexpr int kBlock = 256;
constexpr int kNBlk  = (kCells + kBlock - 1) / kBlock;  // 676 (exact)

__global__ __launch_bounds__(kBlock)
void yolo_loss_main(const float* __restrict__ preds,
                    const float* __restrict__ labels,
                    float* __restrict__ partial) {
    int cell = blockIdx.x * blockDim.x + threadIdx.x;
    float loss = 0.0f;
    if (cell < kCells) {
        const float* lab = labels + (size_t)cell * kC5;
        float obj = lab[4];
        if (obj == 1.0f) {
            float lx = lab[0], ly = lab[1], lw = lab[2], lh = lab[3];
            float lx1 = lx - lw * 0.5f, lx2 = lx + lw * 0.5f;
            float ly1 = ly - lh * 0.5f, ly2 = ly + lh * 0.5f;
            float larea = lw * lh;

            const float* p = preds + (size_t)cell * (kA * kC5);
            float iou[kA], conf[kA];
            int best = 0;
            float bestIou = -1.0f;
            #pragma unroll
            for (int a = 0; a < kA; ++a) {
                const float* pa = p + a * kC5;
                float px = pa[0], py = pa[1], pw = pa[2], ph = pa[3];
                conf[a] = pa[4];
                float px1 = px - pw * 0.5f, px2 = px + pw * 0.5f;
                float py1 = py - ph * 0.5f, py2 = py + ph * 0.5f;
                float iw = fminf(px2, lx2) - fmaxf(px1, lx1);
                float ih = fminf(py2, ly2) - fmaxf(py1, ly1);
                iw = fmaxf(iw, 0.0f);
                ih = fmaxf(ih, 0.0f);
                float inter = iw * ih;
                float uni = pw * ph + larea - inter;
                float v = inter / (uni + 1e-12f);
                iou[a] = v;
                if (v > bestIou) { bestIou = v; best = a; }  // strict > == first-max (jnp.argmax)
            }

            const float* bp = p + best * kC5;
            float bx = bp[0], by = bp[1], bw = bp[2], bh = bp[3], bc = bp[4];

            // loss_xy
            float dx = lx - bx, dy = ly - by;
            loss += 5.0f * (dx * dx + dy * dy);
            // loss_wh
            float sw = sqrtf(lw) - sqrtf(bw);
            float sh = sqrtf(lh) - sqrtf(bh);
            loss += sw * sw + sh * sh;
            // loss_obj
            float dob = bestIou - bc;
            loss += dob * dob;
            // loss_cls
            float cls = 0.0f;
            #pragma unroll
            for (int c = 5; c < kC5; ++c) {
                float d = lab[c] - bp[c];
                cls += d * d;
            }
            loss += cls;
            // loss_noobj: non-best anchors with iou < 0.6, object cells only
            #pragma unroll
            for (int a = 0; a < kA; ++a) {
                if (a != best && iou[a] < 0.6f) {
                    float d = iou[a] - conf[a];
                    loss += d * d;
                }
            }
        }
    }

    // block reduction: wave64 shuffle then LDS
    #pragma unroll
    for (int off = 32; off > 0; off >>= 1)
        loss += __shfl_down(loss, off, 64);
    __shared__ float sred[kBlock / 64];
    int lane = threadIdx.x & 63;
    int wid  = threadIdx.x >> 6;
    if (lane == 0) sred[wid] = loss;
    __syncthreads();
    if (threadIdx.x == 0) {
        float s = 0.0f;
        #pragma unroll
        for (int w = 0; w < kBlock / 64; ++w) s += sred[w];
        partial[blockIdx.x] = s;
    }
}

__global__ __launch_bounds__(kBlock)
void yolo_loss_reduce(const float* __restrict__ partial, float* __restrict__ out) {
    float s = 0.0f;
    for (int i = threadIdx.x; i < kNBlk; i += kBlock) s += partial[i];
    #pragma unroll
    for (int off = 32; off > 0; off >>= 1)
        s += __shfl_down(s, off, 64);
    __shared__ float sred[kBlock / 64];
    int lane = threadIdx.x & 63;
    int wid  = threadIdx.x >> 6;
    if (lane == 0) sred[wid] = s;
    __syncthreads();
    if (threadIdx.x == 0) {
        float t = 0.0f;
        #pragma unroll
        for (int w = 0; w < kBlock / 64; ++w) t += sred[w];
        out[0] = t / (float)kB;
    }
}

extern "C" void kernel_launch(void* const* d_in, const int* in_sizes, int n_in,
                              void* d_out, int out_size, void* d_ws, size_t ws_size,
                              hipStream_t stream) {
    const float* preds  = (const float*)d_in[0];
    const float* labels = (const float*)d_in[1];
    float* out     = (float*)d_out;
    float* partial = (float*)d_ws;   // kNBlk floats = 2704 B of scratch

    yolo_loss_main<<<kNBlk, kBlock, 0, stream>>>(preds, labels, partial);
    yolo_loss_reduce<<<1, kBlock, 0, stream>>>(partial, out);
}